// Round 1
// baseline (534.998 us; speedup 1.0000x reference)
//
#include <hip/hip_runtime.h>

typedef unsigned short u16;
typedef unsigned int u32;
typedef __bf16 bf16x8 __attribute__((ext_vector_type(8)));
typedef float f4_t __attribute__((ext_vector_type(4)));

#define E_DIM 1024
#define L_TOT 4097
#define B_SZ 2
#define M_ROWS 8194   // B*L
#define NWIN 31
#define HHEADS 16

__device__ __forceinline__ float b2f(u16 v) {
  union { u32 u; float f; } x; x.u = ((u32)v) << 16; return x.f;
}
__device__ __forceinline__ u16 f2b(float f) {
  union { float f; u32 u; } x; x.f = f;
  u32 r = (x.u + 0x7FFFu + ((x.u >> 16) & 1u)) >> 16;
  return (u16)r;
}
__device__ __forceinline__ f4_t mfma16(bf16x8 a, bf16x8 b, f4_t c) {
  return __builtin_amdgcn_mfma_f32_16x16x32_bf16(a, b, c, 0, 0, 0);
}

// ---------------- fp32 -> bf16 convert (hidden states) ----------------
__global__ __launch_bounds__(256) void cvt_kernel(const float* __restrict__ src,
                                                  u16* __restrict__ dst, int n4) {
  int i = blockIdx.x * 256 + threadIdx.x;
  if (i >= n4) return;
  float4 v = ((const float4*)src)[i];
  u16 o[4] = {f2b(v.x), f2b(v.y), f2b(v.z), f2b(v.w)};
  *(uint2*)(dst + (size_t)i * 4) = *(uint2*)o;
}

// ---------------- weight transpose + convert: W (K x N) -> Wt (N x K) bf16 ----------------
__global__ __launch_bounds__(256) void wtrans_kernel(const float* __restrict__ w0,
                                                     const float* __restrict__ w1,
                                                     const float* __restrict__ w2,
                                                     const float* __restrict__ w3,
                                                     u16* __restrict__ wtb) {
  const float* src = blockIdx.z == 0 ? w0 : blockIdx.z == 1 ? w1 : blockIdx.z == 2 ? w2 : w3;
  u16* dst = wtb + (size_t)blockIdx.z * E_DIM * E_DIM;
  __shared__ float tile[32][33];
  int tx = threadIdx.x, ty = threadIdx.y;
  int x = blockIdx.x * 32 + tx;
  int y0 = blockIdx.y * 32;
  for (int j = ty; j < 32; j += 8) tile[j][tx] = src[(size_t)(y0 + j) * E_DIM + x];
  __syncthreads();
  // dst[row_out][col_in]: row_out = bx*32+j, col_in = by*32+tx ; = src[by*32+tx][bx*32+j] = tile[tx][j]
  for (int j = ty; j < 32; j += 8)
    dst[(size_t)(blockIdx.x * 32 + j) * E_DIM + blockIdx.y * 32 + tx] = f2b(tile[tx][j]);
}

// ---------------- GEMM: C(MxN) = A(MxK) * Wt^T + bias ; bf16 in, fp32 acc ----------------
// Wt stored N x K (row = output col, contiguous K). K = N = 1024.
template <bool OUTF32>
__global__ __launch_bounds__(256) void gemm_k(const u16* __restrict__ A,
                                              const u16* __restrict__ WtBase, int wsel0,
                                              const float* __restrict__ b0,
                                              const float* __restrict__ b1,
                                              const float* __restrict__ b2,
                                              void* __restrict__ outBase, int M) {
  const int K = 1024, N = 1024;
  int z = blockIdx.z;
  const u16* Wt = WtBase + (size_t)(wsel0 + z) * (K * N);
  const float* bias = (z == 0) ? b0 : (z == 1) ? b1 : b2;

  int bid = blockIdx.x;
  int nt = bid & 7, mt = bid >> 3;
  int m0 = mt * 128, n0 = nt * 128;

  __shared__ u16 As[128][40];
  __shared__ u16 Bs[128][40];

  int t = threadIdx.x;
  int lane = t & 63, w = t >> 6;
  int wr = w >> 1, wc = w & 1;
  int g = lane >> 4, lr = lane & 15;
  int srow = t >> 1, sc = (t & 1) * 16;

  f4_t acc[4][4] = {};

  for (int k0 = 0; k0 < K; k0 += 32) {
    uint4 a0 = make_uint4(0, 0, 0, 0), a1 = make_uint4(0, 0, 0, 0);
    int gr = m0 + srow;
    if (gr < M) {
      const uint4* p = (const uint4*)(A + (size_t)gr * K + k0 + sc);
      a0 = p[0]; a1 = p[1];
    }
    const uint4* q = (const uint4*)(Wt + (size_t)(n0 + srow) * K + k0 + sc);
    uint4 q0 = q[0], q1 = q[1];
    __syncthreads();
    *(uint4*)&As[srow][sc] = a0;
    *(uint4*)&As[srow][sc + 8] = a1;
    *(uint4*)&Bs[srow][sc] = q0;
    *(uint4*)&Bs[srow][sc + 8] = q1;
    __syncthreads();
    bf16x8 av[4], bv[4];
#pragma unroll
    for (int i = 0; i < 4; i++) av[i] = *(const bf16x8*)&As[wr * 64 + i * 16 + lr][g * 8];
#pragma unroll
    for (int j = 0; j < 4; j++) bv[j] = *(const bf16x8*)&Bs[wc * 64 + j * 16 + lr][g * 8];
#pragma unroll
    for (int i = 0; i < 4; i++)
#pragma unroll
      for (int j = 0; j < 4; j++) acc[i][j] = mfma16(av[i], bv[j], acc[i][j]);
  }

#pragma unroll
  for (int j = 0; j < 4; j++) {
    int n = n0 + wc * 64 + j * 16 + lr;
    float bvv = bias[n];
#pragma unroll
    for (int i = 0; i < 4; i++) {
#pragma unroll
      for (int r = 0; r < 4; r++) {
        int m = m0 + wr * 64 + i * 16 + g * 4 + r;
        if (m < M) {
          float val = acc[i][j][r] + bvv;
          if (OUTF32)
            ((float*)outBase)[(size_t)z * 0 + (size_t)m * N + n] = val;
          else
            ((u16*)outBase)[(size_t)z * (size_t)M_ROWS * E_DIM + (size_t)m * N + n] = f2b(val);
        }
      }
    }
  }
}

// ---------------- global attention: token 0 attends over all L tokens ----------------
__global__ __launch_bounds__(256) void gattn_kernel(const u16* __restrict__ Qb,
                                                    const u16* __restrict__ Kb,
                                                    const u16* __restrict__ Vb,
                                                    u16* __restrict__ ctxb) {
  int bh = blockIdx.x;
  int b = bh >> 4, h = bh & 15;
  __shared__ float logit[L_TOT];
  __shared__ float red[4];
  __shared__ float qsh[64];
  __shared__ float cred[4][64];
  int t = threadIdx.x;
  size_t base = (size_t)b * L_TOT * E_DIM + h * 64;

  if (t < 64) qsh[t] = b2f(Qb[base + t]);
  __syncthreads();

  float lmax = -1e30f;
  for (int s = t; s < L_TOT; s += 256) {
    const u16* kp = Kb + base + (size_t)s * E_DIM;
    float acc = 0.f;
#pragma unroll
    for (int c = 0; c < 64; c += 8) {
      uint4 kv = *(const uint4*)(kp + c);
      const u16* kk = (const u16*)&kv;
#pragma unroll
      for (int j = 0; j < 8; j++) acc += qsh[c + j] * b2f(kk[j]);
    }
    acc *= 0.125f;
    logit[s] = acc;
    lmax = fmaxf(lmax, acc);
  }
  for (int mask = 1; mask < 64; mask <<= 1) lmax = fmaxf(lmax, __shfl_xor(lmax, mask));
  if ((t & 63) == 0) red[t >> 6] = lmax;
  __syncthreads();
  lmax = fmaxf(fmaxf(red[0], red[1]), fmaxf(red[2], red[3]));

  float lsum = 0.f;
  for (int s = t; s < L_TOT; s += 256) {
    float p = __expf(logit[s] - lmax);
    logit[s] = p;
    lsum += p;
  }
  for (int mask = 1; mask < 64; mask <<= 1) lsum += __shfl_xor(lsum, mask);
  __syncthreads();
  if ((t & 63) == 0) red[t >> 6] = lsum;
  __syncthreads();
  lsum = red[0] + red[1] + red[2] + red[3];
  float inv = 1.0f / lsum;

  int d = t & 63, gq = t >> 6;
  float acc = 0.f;
  for (int s = gq; s < L_TOT; s += 4) acc += logit[s] * b2f(Vb[base + (size_t)s * E_DIM + d]);
  cred[gq][d] = acc;
  __syncthreads();
  if (gq == 0) {
    float v = (cred[0][d] + cred[1][d] + cred[2][d] + cred[3][d]) * inv;
    ctxb[(size_t)b * L_TOT * E_DIM + h * 64 + d] = f2b(v);
  }
}

// ---------------- windowed attention: one block per (w, h, b) ----------------
__global__ __launch_bounds__(256) void wattn_kernel(const u16* __restrict__ Qb,
                                                    const u16* __restrict__ Kb,
                                                    const u16* __restrict__ Vb,
                                                    u16* __restrict__ winctx) {
  int wdw = blockIdx.x;  // 0..30
  int h = blockIdx.y;    // 0..15
  int b = blockIdx.z;    // 0..1

  __shared__ u16 Ks[256][72];
  __shared__ u16 Vt[64][264];
  __shared__ u16 Ps[64][264];
  __shared__ u16 Qs[64][72];
  __shared__ float lsum[64];

  int t = threadIdx.x, lane = t & 63, wv = t >> 6;
  int g = lane >> 4, lr = lane & 15;
  size_t rowbase = (size_t)b * L_TOT + 1 + (size_t)wdw * 128;
  int hoff = h * 64;

  // stage K (256 x 64), row-major, padded stride 72
#pragma unroll
  for (int pass = 0; pass < 4; pass++) {
    int i = pass * 64 + (t >> 2);
    int c = (t & 3) * 16;
    const uint4* p = (const uint4*)(Kb + (rowbase + i) * E_DIM + hoff + c);
    *(uint4*)&Ks[i][c] = p[0];
    *(uint4*)&Ks[i][c + 8] = p[1];
  }
  // stage V transposed: Vt[d][kpos], padded stride 264
#pragma unroll
  for (int rep = 0; rep < 8; rep++) {
    int u = rep * 256 + t;
    int i = u >> 3;
    int d0 = (u & 7) * 8;
    uint4 v = *(const uint4*)(Vb + (rowbase + i) * E_DIM + hoff + d0);
    const u16* pv = (const u16*)&v;
#pragma unroll
    for (int j = 0; j < 8; j++) Vt[d0 + j][i] = pv[j];
  }
  __syncthreads();

  for (int grp = 0; grp < 4; grp++) {
    // stage Q rows [64*grp, +64)
    {
      int i = t >> 2, c = (t & 3) * 16;
      const uint4* p = (const uint4*)(Qb + (rowbase + grp * 64 + i) * E_DIM + hoff + c);
      *(uint4*)&Qs[i][c] = p[0];
      *(uint4*)&Qs[i][c + 8] = p[1];
    }
    __syncthreads();

    // S phase: wave wv owns q rows [16*wv, 16*wv+16)
    bf16x8 qa0 = *(const bf16x8*)&Qs[wv * 16 + lr][g * 8];
    bf16x8 qa1 = *(const bf16x8*)&Qs[wv * 16 + lr][32 + g * 8];
    f4_t s[16];
#pragma unroll
    for (int ki = 0; ki < 16; ki++) {
      bf16x8 kb0 = *(const bf16x8*)&Ks[ki * 16 + lr][g * 8];
      bf16x8 kb1 = *(const bf16x8*)&Ks[ki * 16 + lr][32 + g * 8];
      f4_t z = {};
      z = mfma16(qa0, kb0, z);
      z = mfma16(qa1, kb1, z);
      s[ki] = z * 0.125f;
    }
    float m[4], sum[4];
#pragma unroll
    for (int r = 0; r < 4; r++) {
      float mx = -1e30f;
#pragma unroll
      for (int ki = 0; ki < 16; ki++) mx = fmaxf(mx, s[ki][r]);
      m[r] = mx;
    }
#pragma unroll
    for (int r = 0; r < 4; r++)
      for (int mask = 1; mask < 16; mask <<= 1) m[r] = fmaxf(m[r], __shfl_xor(m[r], mask));
#pragma unroll
    for (int r = 0; r < 4; r++) sum[r] = 0.f;
#pragma unroll
    for (int ki = 0; ki < 16; ki++) {
#pragma unroll
      for (int r = 0; r < 4; r++) {
        float p = __expf(s[ki][r] - m[r]);
        sum[r] += p;
        Ps[wv * 16 + g * 4 + r][ki * 16 + lr] = f2b(p);
      }
    }
#pragma unroll
    for (int r = 0; r < 4; r++)
      for (int mask = 1; mask < 16; mask <<= 1) sum[r] += __shfl_xor(sum[r], mask);
    if (lr == 0) {
#pragma unroll
      for (int r = 0; r < 4; r++) lsum[wv * 16 + g * 4 + r] = sum[r];
    }
    __syncthreads();

    // PV: wave wv computes d cols [16*wv, +16) for all 64 q rows
    f4_t o[4] = {};
#pragma unroll
    for (int kk = 0; kk < 8; kk++) {
      bf16x8 vb = *(const bf16x8*)&Vt[wv * 16 + lr][kk * 32 + g * 8];
#pragma unroll
      for (int mi = 0; mi < 4; mi++) {
        bf16x8 pa = *(const bf16x8*)&Ps[mi * 16 + lr][kk * 32 + g * 8];
        o[mi] = mfma16(pa, vb, o[mi]);
      }
    }
#pragma unroll
    for (int mi = 0; mi < 4; mi++) {
#pragma unroll
      for (int r = 0; r < 4; r++) {
        int qrow = mi * 16 + g * 4 + r;
        float val = o[mi][r] / lsum[qrow];
        size_t off = (((size_t)(b * NWIN + wdw) * 256 + grp * 64 + qrow) * E_DIM) + hoff + wv * 16 + lr;
        winctx[off] = f2b(val);
      }
    }
    __syncthreads();
  }
}

// ---------------- overlap-average combine: winctx -> ctxb rows 1..4096 ----------------
__global__ __launch_bounds__(256) void combine_kernel(const u16* __restrict__ winctx,
                                                      u16* __restrict__ ctxb) {
  int idx = blockIdx.x * 256 + threadIdx.x;  // 2^20 total
  int e0 = (idx & 127) * 8;
  int p = (idx >> 7) & 4095;
  int b = idx >> 19;
  int whi = p >> 7;
  if (whi > 30) whi = 30;
  int off_hi = p - whi * 128;
  int wlo = whi - 1;
  bool has_lo = (wlo >= 0) && (off_hi < 128);

  uint4 vhi = *(const uint4*)(winctx + (((size_t)(b * NWIN + whi) * 256 + off_hi) * E_DIM) + e0);
  const u16* ph = (const u16*)&vhi;
  float vals[8];
#pragma unroll
  for (int j = 0; j < 8; j++) vals[j] = b2f(ph[j]);
  if (has_lo) {
    uint4 vlo = *(const uint4*)(winctx + (((size_t)(b * NWIN + wlo) * 256 + off_hi + 128) * E_DIM) + e0);
    const u16* pl = (const u16*)&vlo;
#pragma unroll
    for (int j = 0; j < 8; j++) vals[j] = (vals[j] + b2f(pl[j])) * 0.5f;
  }
  u16 out[8];
#pragma unroll
  for (int j = 0; j < 8; j++) out[j] = f2b(vals[j]);
  *(uint4*)(ctxb + ((size_t)b * L_TOT + 1 + p) * E_DIM + e0) = *(uint4*)out;
}

// ---------------- launch ----------------
extern "C" void kernel_launch(void* const* d_in, const int* in_sizes, int n_in,
                              void* d_out, int out_size, void* d_ws, size_t ws_size,
                              hipStream_t stream) {
  const float* hs = (const float*)d_in[0];
  const float* Wq = (const float*)d_in[1];
  const float* bq = (const float*)d_in[2];
  const float* Wk = (const float*)d_in[3];
  const float* bk = (const float*)d_in[4];
  const float* Wv = (const float*)d_in[5];
  const float* bv = (const float*)d_in[6];
  const float* Wo = (const float*)d_in[7];
  const float* bo = (const float*)d_in[8];

  const size_t BLE = (size_t)M_ROWS * E_DIM;          // 8,390,656 elems
  const size_t BLE_B = BLE * 2;                        // bytes bf16
  const size_t EE = (size_t)E_DIM * E_DIM;             // 1,048,576

  char* ws = (char*)d_ws;
  u16* hsb = (u16*)(ws);                               // BLE
  u16* wtb = (u16*)(ws + BLE_B);                       // 4*EE
  u16* qkv = (u16*)(ws + BLE_B + 4 * EE * 2);          // 3*BLE
  u16* Qb = qkv;
  u16* Kb = qkv + BLE;
  u16* Vb = qkv + 2 * BLE;
  u16* ctxb = (u16*)(ws + BLE_B + 4 * EE * 2 + 3 * BLE_B);  // BLE
  u16* winctx = (u16*)(ws + BLE_B + 4 * EE * 2 + 4 * BLE_B); // B*31*256*E

  // 1. convert hidden states to bf16
  cvt_kernel<<<8194, 256, 0, stream>>>(hs, hsb, (int)(BLE / 4));
  // 2. transpose+convert weights
  wtrans_kernel<<<dim3(32, 32, 4), dim3(32, 8), 0, stream>>>(Wq, Wk, Wv, Wo, wtb);
  // 3. QKV projections (z = 0,1,2)
  gemm_k<false><<<dim3(520, 1, 3), 256, 0, stream>>>(hsb, wtb, 0, bq, bk, bv, qkv, M_ROWS);
  // 4. global attention (row 0 of each batch in ctxb)
  gattn_kernel<<<32, 256, 0, stream>>>(Qb, Kb, Vb, ctxb);
  // 5. windowed attention
  wattn_kernel<<<dim3(NWIN, HHEADS, B_SZ), 256, 0, stream>>>(Qb, Kb, Vb, winctx);
  // 6. overlap-average into ctxb rows 1..4096
  combine_kernel<<<4096, 256, 0, stream>>>(winctx, ctxb);
  // 7. output projection -> fp32 d_out
  gemm_k<true><<<dim3(520, 1, 1), 256, 0, stream>>>(ctxb, wtb, 3, bo, bo, bo, d_out, M_ROWS);
}

// Round 2
// 291.173 us; speedup vs baseline: 1.8374x; 1.8374x over previous
//
#include <hip/hip_runtime.h>

typedef unsigned short u16;
typedef unsigned int u32;
typedef __bf16 bf16x8 __attribute__((ext_vector_type(8)));
typedef float f4_t __attribute__((ext_vector_type(4)));

#define E_DIM 1024
#define L_TOT 4097
#define B_SZ 2
#define M_ROWS 8194   // B*L
#define NWIN 31
#define HHEADS 16
#define GCHUNKS 17    // ceil(4097/256)

__device__ __forceinline__ float b2f(u16 v) {
  union { u32 u; float f; } x; x.u = ((u32)v) << 16; return x.f;
}
__device__ __forceinline__ u16 f2b(float f) {
  union { float f; u32 u; } x; x.f = f;
  u32 r = (x.u + 0x7FFFu + ((x.u >> 16) & 1u)) >> 16;
  return (u16)r;
}
__device__ __forceinline__ f4_t mfma16(bf16x8 a, bf16x8 b, f4_t c) {
  return __builtin_amdgcn_mfma_f32_16x16x32_bf16(a, b, c, 0, 0, 0);
}

// ---------------- fp32 -> bf16 convert (hidden states) ----------------
__global__ __launch_bounds__(256) void cvt_kernel(const float* __restrict__ src,
                                                  u16* __restrict__ dst, int n4) {
  int i = blockIdx.x * 256 + threadIdx.x;
  if (i >= n4) return;
  float4 v = ((const float4*)src)[i];
  u16 o[4] = {f2b(v.x), f2b(v.y), f2b(v.z), f2b(v.w)};
  *(uint2*)(dst + (size_t)i * 4) = *(uint2*)o;
}

// ---------------- weight transpose + convert: W (K x N) -> Wt (N x K) bf16 ----------------
__global__ __launch_bounds__(256) void wtrans_kernel(const float* __restrict__ w0,
                                                     const float* __restrict__ w1,
                                                     const float* __restrict__ w2,
                                                     const float* __restrict__ w3,
                                                     u16* __restrict__ wtb) {
  const float* src = blockIdx.z == 0 ? w0 : blockIdx.z == 1 ? w1 : blockIdx.z == 2 ? w2 : w3;
  u16* dst = wtb + (size_t)blockIdx.z * E_DIM * E_DIM;
  __shared__ float tile[32][33];
  int tx = threadIdx.x, ty = threadIdx.y;
  int x = blockIdx.x * 32 + tx;
  int y0 = blockIdx.y * 32;
  for (int j = ty; j < 32; j += 8) tile[j][tx] = src[(size_t)(y0 + j) * E_DIM + x];
  __syncthreads();
  for (int j = ty; j < 32; j += 8)
    dst[(size_t)(blockIdx.x * 32 + j) * E_DIM + blockIdx.y * 32 + tx] = f2b(tile[tx][j]);
}

// ---------------- GEMM: C(MxN) = A(MxK) * Wt^T + bias ; bf16 in, fp32 acc ----------------
template <bool OUTF32>
__global__ __launch_bounds__(256) void gemm_k(const u16* __restrict__ A,
                                              const u16* __restrict__ WtBase, int wsel0,
                                              const float* __restrict__ b0,
                                              const float* __restrict__ b1,
                                              const float* __restrict__ b2,
                                              void* __restrict__ outBase, int M) {
  const int K = 1024, N = 1024;
  int z = blockIdx.z;
  const u16* Wt = WtBase + (size_t)(wsel0 + z) * (K * N);
  const float* bias = (z == 0) ? b0 : (z == 1) ? b1 : b2;

  int bid = blockIdx.x;
  int nt = bid & 7, mt = bid >> 3;
  int m0 = mt * 128, n0 = nt * 128;

  __shared__ u16 As[128][40];
  __shared__ u16 Bs[128][40];

  int t = threadIdx.x;
  int lane = t & 63, w = t >> 6;
  int wr = w >> 1, wc = w & 1;
  int g = lane >> 4, lr = lane & 15;
  int srow = t >> 1, sc = (t & 1) * 16;

  f4_t acc[4][4] = {};

  for (int k0 = 0; k0 < K; k0 += 32) {
    uint4 a0 = make_uint4(0, 0, 0, 0), a1 = make_uint4(0, 0, 0, 0);
    int gr = m0 + srow;
    if (gr < M) {
      const uint4* p = (const uint4*)(A + (size_t)gr * K + k0 + sc);
      a0 = p[0]; a1 = p[1];
    }
    const uint4* q = (const uint4*)(Wt + (size_t)(n0 + srow) * K + k0 + sc);
    uint4 q0 = q[0], q1 = q[1];
    __syncthreads();
    *(uint4*)&As[srow][sc] = a0;
    *(uint4*)&As[srow][sc + 8] = a1;
    *(uint4*)&Bs[srow][sc] = q0;
    *(uint4*)&Bs[srow][sc + 8] = q1;
    __syncthreads();
    bf16x8 av[4], bv[4];
#pragma unroll
    for (int i = 0; i < 4; i++) av[i] = *(const bf16x8*)&As[wr * 64 + i * 16 + lr][g * 8];
#pragma unroll
    for (int j = 0; j < 4; j++) bv[j] = *(const bf16x8*)&Bs[wc * 64 + j * 16 + lr][g * 8];
#pragma unroll
    for (int i = 0; i < 4; i++)
#pragma unroll
      for (int j = 0; j < 4; j++) acc[i][j] = mfma16(av[i], bv[j], acc[i][j]);
  }

#pragma unroll
  for (int j = 0; j < 4; j++) {
    int n = n0 + wc * 64 + j * 16 + lr;
    float bvv = bias[n];
#pragma unroll
    for (int i = 0; i < 4; i++) {
#pragma unroll
      for (int r = 0; r < 4; r++) {
        int m = m0 + wr * 64 + i * 16 + g * 4 + r;
        if (m < M) {
          float val = acc[i][j][r] + bvv;
          if (OUTF32)
            ((float*)outBase)[(size_t)m * N + n] = val;
          else
            ((u16*)outBase)[(size_t)z * (size_t)M_ROWS * E_DIM + (size_t)m * N + n] = f2b(val);
        }
      }
    }
  }
}

// ---------------- global attention, phase 1: per-chunk partials ----------------
// part layout per (b,h,c): [0..63] = unnormalized ctx partial, [64] = m_c, [65] = s_c
__global__ __launch_bounds__(256) void gattn1_kernel(const u16* __restrict__ Qb,
                                                     const u16* __restrict__ Kb,
                                                     const u16* __restrict__ Vb,
                                                     float* __restrict__ part) {
  int c = blockIdx.x;   // 0..16
  int h = blockIdx.y;
  int b = blockIdx.z;
  int t = threadIdx.x;
  __shared__ float qsh[64];
  __shared__ float red[4];
  __shared__ float psh[256];
  __shared__ float cred[4][64];

  size_t base = (size_t)b * L_TOT * E_DIM + h * 64;
  if (t < 64) qsh[t] = b2f(Qb[base + t]);
  __syncthreads();

  int row = c * 256 + t;
  bool valid = row < L_TOT;
  float dot = -1e30f;
  if (valid) {
    const u16* kp = Kb + base + (size_t)row * E_DIM;
    float acc = 0.f;
#pragma unroll
    for (int j = 0; j < 64; j += 8) {
      uint4 kv = *(const uint4*)(kp + j);
      const u16* kk = (const u16*)&kv;
#pragma unroll
      for (int q = 0; q < 8; q++) acc += qsh[j + q] * b2f(kk[q]);
    }
    dot = acc * 0.125f;
  }
  float m = dot;
  for (int mask = 1; mask < 64; mask <<= 1) m = fmaxf(m, __shfl_xor(m, mask));
  if ((t & 63) == 0) red[t >> 6] = m;
  __syncthreads();
  m = fmaxf(fmaxf(red[0], red[1]), fmaxf(red[2], red[3]));
  float p = valid ? __expf(dot - m) : 0.f;
  psh[t] = p;
  float s = p;
  for (int mask = 1; mask < 64; mask <<= 1) s += __shfl_xor(s, mask);
  __syncthreads();
  if ((t & 63) == 0) red[t >> 6] = s;
  __syncthreads();
  s = red[0] + red[1] + red[2] + red[3];

  // PV partial: group gq handles 64 rows, lane d accumulates one dim
  int d = t & 63, gq = t >> 6;
  float acc = 0.f;
#pragma unroll 4
  for (int i = 0; i < 64; i++) {
    int sl = gq * 64 + i;
    int r2 = c * 256 + sl;
    if (r2 < L_TOT) acc += psh[sl] * b2f(Vb[base + (size_t)r2 * E_DIM + d]);
  }
  cred[gq][d] = acc;
  __syncthreads();
  if (t < 64) {
    float v = cred[0][t] + cred[1][t] + cred[2][t] + cred[3][t];
    float* pp = part + (((size_t)(b * HHEADS + h) * GCHUNKS + c) * 66);
    pp[t] = v;
    if (t == 0) { pp[64] = m; pp[65] = s; }
  }
}

// ---------------- global attention, phase 2: combine chunks ----------------
__global__ __launch_bounds__(64) void gattn2_kernel(const float* __restrict__ part,
                                                    u16* __restrict__ ctxb) {
  int bh = blockIdx.x;
  int b = bh >> 4, h = bh & 15;
  int d = threadIdx.x;  // 0..63
  const float* pp = part + ((size_t)(b * HHEADS + h) * GCHUNKS) * 66;
  float m = -1e30f;
#pragma unroll
  for (int c = 0; c < GCHUNKS; c++) m = fmaxf(m, pp[c * 66 + 64]);
  float stot = 0.f, acc = 0.f;
#pragma unroll
  for (int c = 0; c < GCHUNKS; c++) {
    float w = __expf(pp[c * 66 + 64] - m);
    stot += pp[c * 66 + 65] * w;
    acc += pp[c * 66 + d] * w;
  }
  ctxb[(size_t)b * L_TOT * E_DIM + h * 64 + d] = f2b(acc / stot);
}

// ---------------- windowed attention: one block per (w, h, b) ----------------
__global__ __launch_bounds__(256) void wattn_kernel(const u16* __restrict__ Qb,
                                                    const u16* __restrict__ Kb,
                                                    const u16* __restrict__ Vb,
                                                    u16* __restrict__ winctx) {
  int wdw = blockIdx.x;  // 0..30
  int h = blockIdx.y;    // 0..15
  int b = blockIdx.z;    // 0..1

  __shared__ u16 Ks[256][72];
  __shared__ u16 Vt[64][264];
  __shared__ u16 Ps[64][264];
  __shared__ u16 Qs[64][72];
  __shared__ float lsum[64];

  int t = threadIdx.x, lane = t & 63, wv = t >> 6;
  int g = lane >> 4, lr = lane & 15;
  size_t rowbase = (size_t)b * L_TOT + 1 + (size_t)wdw * 128;
  int hoff = h * 64;

#pragma unroll
  for (int pass = 0; pass < 4; pass++) {
    int i = pass * 64 + (t >> 2);
    int c = (t & 3) * 16;
    const uint4* p = (const uint4*)(Kb + (rowbase + i) * E_DIM + hoff + c);
    *(uint4*)&Ks[i][c] = p[0];
    *(uint4*)&Ks[i][c + 8] = p[1];
  }
#pragma unroll
  for (int rep = 0; rep < 8; rep++) {
    int u = rep * 256 + t;
    int i = u >> 3;
    int d0 = (u & 7) * 8;
    uint4 v = *(const uint4*)(Vb + (rowbase + i) * E_DIM + hoff + d0);
    const u16* pv = (const u16*)&v;
#pragma unroll
    for (int j = 0; j < 8; j++) Vt[d0 + j][i] = pv[j];
  }
  __syncthreads();

  for (int grp = 0; grp < 4; grp++) {
    {
      int i = t >> 2, c = (t & 3) * 16;
      const uint4* p = (const uint4*)(Qb + (rowbase + grp * 64 + i) * E_DIM + hoff + c);
      *(uint4*)&Qs[i][c] = p[0];
      *(uint4*)&Qs[i][c + 8] = p[1];
    }
    __syncthreads();

    bf16x8 qa0 = *(const bf16x8*)&Qs[wv * 16 + lr][g * 8];
    bf16x8 qa1 = *(const bf16x8*)&Qs[wv * 16 + lr][32 + g * 8];
    f4_t s[16];
#pragma unroll
    for (int ki = 0; ki < 16; ki++) {
      bf16x8 kb0 = *(const bf16x8*)&Ks[ki * 16 + lr][g * 8];
      bf16x8 kb1 = *(const bf16x8*)&Ks[ki * 16 + lr][32 + g * 8];
      f4_t z = {};
      z = mfma16(qa0, kb0, z);
      z = mfma16(qa1, kb1, z);
      s[ki] = z * 0.125f;
    }
    float m[4], sum[4];
#pragma unroll
    for (int r = 0; r < 4; r++) {
      float mx = -1e30f;
#pragma unroll
      for (int ki = 0; ki < 16; ki++) mx = fmaxf(mx, s[ki][r]);
      m[r] = mx;
    }
#pragma unroll
    for (int r = 0; r < 4; r++)
      for (int mask = 1; mask < 16; mask <<= 1) m[r] = fmaxf(m[r], __shfl_xor(m[r], mask));
#pragma unroll
    for (int r = 0; r < 4; r++) sum[r] = 0.f;
#pragma unroll
    for (int ki = 0; ki < 16; ki++) {
#pragma unroll
      for (int r = 0; r < 4; r++) {
        float p = __expf(s[ki][r] - m[r]);
        sum[r] += p;
        Ps[wv * 16 + g * 4 + r][ki * 16 + lr] = f2b(p);
      }
    }
#pragma unroll
    for (int r = 0; r < 4; r++)
      for (int mask = 1; mask < 16; mask <<= 1) sum[r] += __shfl_xor(sum[r], mask);
    if (lr == 0) {
#pragma unroll
      for (int r = 0; r < 4; r++) lsum[wv * 16 + g * 4 + r] = sum[r];
    }
    __syncthreads();

    f4_t o[4] = {};
#pragma unroll
    for (int kk = 0; kk < 8; kk++) {
      bf16x8 vb = *(const bf16x8*)&Vt[wv * 16 + lr][kk * 32 + g * 8];
#pragma unroll
      for (int mi = 0; mi < 4; mi++) {
        bf16x8 pa = *(const bf16x8*)&Ps[mi * 16 + lr][kk * 32 + g * 8];
        o[mi] = mfma16(pa, vb, o[mi]);
      }
    }
#pragma unroll
    for (int mi = 0; mi < 4; mi++) {
#pragma unroll
      for (int r = 0; r < 4; r++) {
        int qrow = mi * 16 + g * 4 + r;
        float val = o[mi][r] / lsum[qrow];
        size_t off = (((size_t)(b * NWIN + wdw) * 256 + grp * 64 + qrow) * E_DIM) + hoff + wv * 16 + lr;
        winctx[off] = f2b(val);
      }
    }
    __syncthreads();
  }
}

// ---------------- overlap-average combine: winctx -> ctxb rows 1..4096 ----------------
__global__ __launch_bounds__(256) void combine_kernel(const u16* __restrict__ winctx,
                                                      u16* __restrict__ ctxb) {
  int idx = blockIdx.x * 256 + threadIdx.x;  // 2^20 total
  int e0 = (idx & 127) * 8;
  int p = (idx >> 7) & 4095;
  int b = idx >> 19;
  int whi = p >> 7;
  if (whi > 30) whi = 30;
  int off_hi = p - whi * 128;
  int wlo = whi - 1;
  bool has_lo = (wlo >= 0) && (off_hi < 128);

  uint4 vhi = *(const uint4*)(winctx + (((size_t)(b * NWIN + whi) * 256 + off_hi) * E_DIM) + e0);
  const u16* ph = (const u16*)&vhi;
  float vals[8];
#pragma unroll
  for (int j = 0; j < 8; j++) vals[j] = b2f(ph[j]);
  if (has_lo) {
    uint4 vlo = *(const uint4*)(winctx + (((size_t)(b * NWIN + wlo) * 256 + off_hi + 128) * E_DIM) + e0);
    const u16* pl = (const u16*)&vlo;
#pragma unroll
    for (int j = 0; j < 8; j++) vals[j] = (vals[j] + b2f(pl[j])) * 0.5f;
  }
  u16 out[8];
#pragma unroll
  for (int j = 0; j < 8; j++) out[j] = f2b(vals[j]);
  *(uint4*)(ctxb + ((size_t)b * L_TOT + 1 + p) * E_DIM + e0) = *(uint4*)out;
}

// ---------------- launch ----------------
extern "C" void kernel_launch(void* const* d_in, const int* in_sizes, int n_in,
                              void* d_out, int out_size, void* d_ws, size_t ws_size,
                              hipStream_t stream) {
  const float* hs = (const float*)d_in[0];
  const float* Wq = (const float*)d_in[1];
  const float* bq = (const float*)d_in[2];
  const float* Wk = (const float*)d_in[3];
  const float* bk = (const float*)d_in[4];
  const float* Wv = (const float*)d_in[5];
  const float* bv = (const float*)d_in[6];
  const float* Wo = (const float*)d_in[7];
  const float* bo = (const float*)d_in[8];

  const size_t BLE = (size_t)M_ROWS * E_DIM;
  const size_t BLE_B = BLE * 2;
  const size_t EE = (size_t)E_DIM * E_DIM;

  char* ws = (char*)d_ws;
  u16* hsb = (u16*)(ws);
  u16* wtb = (u16*)(ws + BLE_B);
  u16* qkv = (u16*)(ws + BLE_B + 4 * EE * 2);
  u16* Qb = qkv;
  u16* Kb = qkv + BLE;
  u16* Vb = qkv + 2 * BLE;
  u16* ctxb = (u16*)(ws + BLE_B + 4 * EE * 2 + 3 * BLE_B);
  u16* winctx = (u16*)(ws + BLE_B + 4 * EE * 2 + 4 * BLE_B);           // B*31*256*E bf16
  float* gpart = (float*)(ws + BLE_B + 4 * EE * 2 + 4 * BLE_B +
                          (size_t)B_SZ * NWIN * 256 * E_DIM * 2);      // B*H*17*66 fp32

  cvt_kernel<<<8194, 256, 0, stream>>>(hs, hsb, (int)(BLE / 4));
  wtrans_kernel<<<dim3(32, 32, 4), dim3(32, 8), 0, stream>>>(Wq, Wk, Wv, Wo, wtb);
  gemm_k<false><<<dim3(520, 1, 3), 256, 0, stream>>>(hsb, wtb, 0, bq, bk, bv, qkv, M_ROWS);
  gattn1_kernel<<<dim3(GCHUNKS, HHEADS, B_SZ), 256, 0, stream>>>(Qb, Kb, Vb, gpart);
  gattn2_kernel<<<32, 64, 0, stream>>>(gpart, ctxb);
  wattn_kernel<<<dim3(NWIN, HHEADS, B_SZ), 256, 0, stream>>>(Qb, Kb, Vb, winctx);
  combine_kernel<<<4096, 256, 0, stream>>>(winctx, ctxb);
  gemm_k<true><<<dim3(520, 1, 1), 256, 0, stream>>>(ctxb, wtb, 3, bo, bo, bo, d_out, M_ROWS);
}

// Round 3
// 268.308 us; speedup vs baseline: 1.9940x; 1.0852x over previous
//
#include <hip/hip_runtime.h>

typedef unsigned short u16;
typedef unsigned int u32;
typedef __bf16 bf16x8 __attribute__((ext_vector_type(8)));
typedef float f4_t __attribute__((ext_vector_type(4)));

#define E_DIM 1024
#define L_TOT 4097
#define B_SZ 2
#define M_ROWS 8194   // B*L
#define NWIN 31
#define HHEADS 16
#define GCHUNKS 17    // ceil(4097/256)

__device__ __forceinline__ float b2f(u16 v) {
  union { u32 u; float f; } x; x.u = ((u32)v) << 16; return x.f;
}
__device__ __forceinline__ u16 f2b(float f) {
  union { float f; u32 u; } x; x.f = f;
  u32 r = (x.u + 0x7FFFu + ((x.u >> 16) & 1u)) >> 16;
  return (u16)r;
}
__device__ __forceinline__ f4_t mfma16(bf16x8 a, bf16x8 b, f4_t c) {
  return __builtin_amdgcn_mfma_f32_16x16x32_bf16(a, b, c, 0, 0, 0);
}

// async global->LDS, 16B per lane; LDS dest = wave-uniform base + lane*16
#define GLOAD16(gp, lp)                                                              \
  __builtin_amdgcn_global_load_lds(                                                  \
      (const __attribute__((address_space(1))) u32*)(gp),                            \
      (__attribute__((address_space(3))) u32*)(lp), 16, 0, 0)

// ---------------- fp32 -> bf16 convert (hidden states) ----------------
__global__ __launch_bounds__(256) void cvt_kernel(const float* __restrict__ src,
                                                  u16* __restrict__ dst, int n4) {
  int i = blockIdx.x * 256 + threadIdx.x;
  if (i >= n4) return;
  float4 v = ((const float4*)src)[i];
  u16 o[4] = {f2b(v.x), f2b(v.y), f2b(v.z), f2b(v.w)};
  *(uint2*)(dst + (size_t)i * 4) = *(uint2*)o;
}

// ---------------- weight transpose + convert: W (K x N) -> Wt (N x K) bf16 ----------------
__global__ __launch_bounds__(256) void wtrans_kernel(const float* __restrict__ w0,
                                                     const float* __restrict__ w1,
                                                     const float* __restrict__ w2,
                                                     const float* __restrict__ w3,
                                                     u16* __restrict__ wtb) {
  const float* src = blockIdx.z == 0 ? w0 : blockIdx.z == 1 ? w1 : blockIdx.z == 2 ? w2 : w3;
  u16* dst = wtb + (size_t)blockIdx.z * E_DIM * E_DIM;
  __shared__ float tile[32][33];
  int tx = threadIdx.x, ty = threadIdx.y;
  int x = blockIdx.x * 32 + tx;
  int y0 = blockIdx.y * 32;
  for (int j = ty; j < 32; j += 8) tile[j][tx] = src[(size_t)(y0 + j) * E_DIM + x];
  __syncthreads();
  for (int j = ty; j < 32; j += 8)
    dst[(size_t)(blockIdx.x * 32 + j) * E_DIM + blockIdx.y * 32 + tx] = f2b(tile[tx][j]);
}

// ---------------- GEMM (m97 structure): C(M x NT*128) = A(M x 1024) * Wt^T + bias ----------------
// Wt stored [NT*128][1024] row-major (row = output col, contiguous K).
// MODE 0: bf16 out demuxed to 3 tensors of [M_ROWS][1024] (QKV). MODE 1: fp32 out single.
// LDS: linear [128][32] per operand; logical slot s of row r stored at physical
// slot s ^ ((r ^ (r>>2)) & 3). Source lanes pre-swizzled, fragment reads swizzled.
template <int MODE>
__global__ __launch_bounds__(256) void gemm2_kernel(const u16* __restrict__ A,
                                                    const u16* __restrict__ Wt,
                                                    const float* __restrict__ b0,
                                                    const float* __restrict__ b1,
                                                    const float* __restrict__ b2,
                                                    void* __restrict__ outBase,
                                                    int M, int NT) {
  __shared__ u16 As[128 * 32];
  __shared__ u16 Bs[128 * 32];

  // bijective XCD swizzle (gridDim.x % 8 == 0), n-fast within each XCD chunk
  int nwg = gridDim.x;
  int cpx = nwg >> 3;
  int orig = blockIdx.x;
  int wg = (orig & 7) * cpx + (orig >> 3);
  int mt = wg / NT, nt = wg - mt * NT;
  int m0 = mt * 128, n0 = nt * 128;

  int t = threadIdx.x, lane = t & 63, w = t >> 6;
  int wr = w >> 1, wc = w & 1;
  int g = lane >> 4, lr = lane & 15;

  // staging geometry: lane covers row rsub (within 16-row chunk), pre-swizzled col
  int rsub = lane >> 2;
  int colE = (((lane & 3) ^ (lane >> 2) ^ (lane >> 4)) & 3) << 3;
  int c0 = w * 2, c1 = c0 + 1;

  int ra0 = m0 + c0 * 16 + rsub; ra0 = ra0 < M ? ra0 : M - 1;
  int ra1 = m0 + c1 * 16 + rsub; ra1 = ra1 < M ? ra1 : M - 1;
  const u16* pA0 = A + (size_t)ra0 * 1024 + colE;
  const u16* pA1 = A + (size_t)ra1 * 1024 + colE;
  const u16* pB0 = Wt + (size_t)(n0 + c0 * 16 + rsub) * 1024 + colE;
  const u16* pB1 = Wt + (size_t)(n0 + c1 * 16 + rsub) * 1024 + colE;
  u16* lA0 = As + c0 * 512;
  u16* lA1 = As + c1 * 512;
  u16* lB0 = Bs + c0 * 512;
  u16* lB1 = Bs + c1 * 512;

  int offA = ((g ^ ((lr ^ (lr >> 2)) & 3)) << 3);  // swizzled slot within row

  f4_t acc[4][4] = {};

  for (int k0 = 0; k0 < 1024; k0 += 32) {
    GLOAD16(pA0 + k0, lA0);
    GLOAD16(pA1 + k0, lA1);
    GLOAD16(pB0 + k0, lB0);
    GLOAD16(pB1 + k0, lB1);
    __syncthreads();  // drains vmcnt -> staged data visible
    bf16x8 av[4], bv[4];
#pragma unroll
    for (int i = 0; i < 4; i++)
      av[i] = *(const bf16x8*)&As[(wr * 64 + i * 16 + lr) * 32 + offA];
#pragma unroll
    for (int j = 0; j < 4; j++)
      bv[j] = *(const bf16x8*)&Bs[(wc * 64 + j * 16 + lr) * 32 + offA];
#pragma unroll
    for (int i = 0; i < 4; i++)
#pragma unroll
      for (int j = 0; j < 4; j++)
        acc[i][j] = mfma16(av[i], bv[j], acc[i][j]);
    __syncthreads();  // all reads done before next stage overwrites
  }

#pragma unroll
  for (int j = 0; j < 4; j++) {
    int n = n0 + wc * 64 + j * 16 + lr;
    if (MODE == 0) {
      int tsel = n >> 10, ncol = n & 1023;
      const float* bp = tsel == 0 ? b0 : (tsel == 1 ? b1 : b2);
      float bb = bp[ncol];
      u16* op = (u16*)outBase + (size_t)tsel * ((size_t)M_ROWS * E_DIM) + ncol;
#pragma unroll
      for (int i = 0; i < 4; i++) {
        int mbase = m0 + wr * 64 + i * 16 + g * 4;
#pragma unroll
        for (int r = 0; r < 4; r++) {
          int m = mbase + r;
          if (m < M) op[(size_t)m * E_DIM] = f2b(acc[i][j][r] + bb);
        }
      }
    } else {
      float bb = b0[n];
      float* op = (float*)outBase + n;
#pragma unroll
      for (int i = 0; i < 4; i++) {
        int mbase = m0 + wr * 64 + i * 16 + g * 4;
#pragma unroll
        for (int r = 0; r < 4; r++) {
          int m = mbase + r;
          if (m < M) op[(size_t)m * E_DIM] = acc[i][j][r] + bb;
        }
      }
    }
  }
}

// ---------------- global attention, phase 1: per-chunk partials ----------------
__global__ __launch_bounds__(256) void gattn1_kernel(const u16* __restrict__ Qb,
                                                     const u16* __restrict__ Kb,
                                                     const u16* __restrict__ Vb,
                                                     float* __restrict__ part) {
  int c = blockIdx.x;
  int h = blockIdx.y;
  int b = blockIdx.z;
  int t = threadIdx.x;
  __shared__ float qsh[64];
  __shared__ float red[4];
  __shared__ float psh[256];
  __shared__ float cred[4][64];

  size_t base = (size_t)b * L_TOT * E_DIM + h * 64;
  if (t < 64) qsh[t] = b2f(Qb[base + t]);
  __syncthreads();

  int row = c * 256 + t;
  bool valid = row < L_TOT;
  float dot = -1e30f;
  if (valid) {
    const u16* kp = Kb + base + (size_t)row * E_DIM;
    float acc = 0.f;
#pragma unroll
    for (int j = 0; j < 64; j += 8) {
      uint4 kv = *(const uint4*)(kp + j);
      const u16* kk = (const u16*)&kv;
#pragma unroll
      for (int q = 0; q < 8; q++) acc += qsh[j + q] * b2f(kk[q]);
    }
    dot = acc * 0.125f;
  }
  float m = dot;
  for (int mask = 1; mask < 64; mask <<= 1) m = fmaxf(m, __shfl_xor(m, mask));
  if ((t & 63) == 0) red[t >> 6] = m;
  __syncthreads();
  m = fmaxf(fmaxf(red[0], red[1]), fmaxf(red[2], red[3]));
  float p = valid ? __expf(dot - m) : 0.f;
  psh[t] = p;
  float s = p;
  for (int mask = 1; mask < 64; mask <<= 1) s += __shfl_xor(s, mask);
  __syncthreads();
  if ((t & 63) == 0) red[t >> 6] = s;
  __syncthreads();
  s = red[0] + red[1] + red[2] + red[3];

  int d = t & 63, gq = t >> 6;
  float acc = 0.f;
#pragma unroll 4
  for (int i = 0; i < 64; i++) {
    int sl = gq * 64 + i;
    int r2 = c * 256 + sl;
    if (r2 < L_TOT) acc += psh[sl] * b2f(Vb[base + (size_t)r2 * E_DIM + d]);
  }
  cred[gq][d] = acc;
  __syncthreads();
  if (t < 64) {
    float v = cred[0][t] + cred[1][t] + cred[2][t] + cred[3][t];
    float* pp = part + (((size_t)(b * HHEADS + h) * GCHUNKS + c) * 66);
    pp[t] = v;
    if (t == 0) { pp[64] = m; pp[65] = s; }
  }
}

// ---------------- global attention, phase 2: combine chunks ----------------
__global__ __launch_bounds__(64) void gattn2_kernel(const float* __restrict__ part,
                                                    u16* __restrict__ ctxb) {
  int bh = blockIdx.x;
  int b = bh >> 4, h = bh & 15;
  int d = threadIdx.x;
  const float* pp = part + ((size_t)(b * HHEADS + h) * GCHUNKS) * 66;
  float m = -1e30f;
#pragma unroll
  for (int c = 0; c < GCHUNKS; c++) m = fmaxf(m, pp[c * 66 + 64]);
  float stot = 0.f, acc = 0.f;
#pragma unroll
  for (int c = 0; c < GCHUNKS; c++) {
    float w = __expf(pp[c * 66 + 64] - m);
    stot += pp[c * 66 + 65] * w;
    acc += pp[c * 66 + d] * w;
  }
  ctxb[(size_t)b * L_TOT * E_DIM + h * 64 + d] = f2b(acc / stot);
}

// ---------------- windowed attention: one block per (w, h, b) ----------------
__global__ __launch_bounds__(256) void wattn_kernel(const u16* __restrict__ Qb,
                                                    const u16* __restrict__ Kb,
                                                    const u16* __restrict__ Vb,
                                                    u16* __restrict__ winctx) {
  int wdw = blockIdx.x;
  int h = blockIdx.y;
  int b = blockIdx.z;

  __shared__ u16 Ks[256][72];
  __shared__ u16 Vt[64][264];
  __shared__ u16 Ps[64][264];
  __shared__ u16 Qs[64][72];
  __shared__ float lsum[64];

  int t = threadIdx.x, lane = t & 63, wv = t >> 6;
  int g = lane >> 4, lr = lane & 15;
  size_t rowbase = (size_t)b * L_TOT + 1 + (size_t)wdw * 128;
  int hoff = h * 64;

#pragma unroll
  for (int pass = 0; pass < 4; pass++) {
    int i = pass * 64 + (t >> 2);
    int c = (t & 3) * 16;
    const uint4* p = (const uint4*)(Kb + (rowbase + i) * E_DIM + hoff + c);
    *(uint4*)&Ks[i][c] = p[0];
    *(uint4*)&Ks[i][c + 8] = p[1];
  }
#pragma unroll
  for (int rep = 0; rep < 8; rep++) {
    int u = rep * 256 + t;
    int i = u >> 3;
    int d0 = (u & 7) * 8;
    uint4 v = *(const uint4*)(Vb + (rowbase + i) * E_DIM + hoff + d0);
    const u16* pv = (const u16*)&v;
#pragma unroll
    for (int j = 0; j < 8; j++) Vt[d0 + j][i] = pv[j];
  }
  __syncthreads();

  for (int grp = 0; grp < 4; grp++) {
    {
      int i = t >> 2, c = (t & 3) * 16;
      const uint4* p = (const uint4*)(Qb + (rowbase + grp * 64 + i) * E_DIM + hoff + c);
      *(uint4*)&Qs[i][c] = p[0];
      *(uint4*)&Qs[i][c + 8] = p[1];
    }
    __syncthreads();

    bf16x8 qa0 = *(const bf16x8*)&Qs[wv * 16 + lr][g * 8];
    bf16x8 qa1 = *(const bf16x8*)&Qs[wv * 16 + lr][32 + g * 8];
    f4_t s[16];
#pragma unroll
    for (int ki = 0; ki < 16; ki++) {
      bf16x8 kb0 = *(const bf16x8*)&Ks[ki * 16 + lr][g * 8];
      bf16x8 kb1 = *(const bf16x8*)&Ks[ki * 16 + lr][32 + g * 8];
      f4_t z = {};
      z = mfma16(qa0, kb0, z);
      z = mfma16(qa1, kb1, z);
      s[ki] = z * 0.125f;
    }
    float m[4], sum[4];
#pragma unroll
    for (int r = 0; r < 4; r++) {
      float mx = -1e30f;
#pragma unroll
      for (int ki = 0; ki < 16; ki++) mx = fmaxf(mx, s[ki][r]);
      m[r] = mx;
    }
#pragma unroll
    for (int r = 0; r < 4; r++)
      for (int mask = 1; mask < 16; mask <<= 1) m[r] = fmaxf(m[r], __shfl_xor(m[r], mask));
#pragma unroll
    for (int r = 0; r < 4; r++) sum[r] = 0.f;
#pragma unroll
    for (int ki = 0; ki < 16; ki++) {
#pragma unroll
      for (int r = 0; r < 4; r++) {
        float p = __expf(s[ki][r] - m[r]);
        sum[r] += p;
        Ps[wv * 16 + g * 4 + r][ki * 16 + lr] = f2b(p);
      }
    }
#pragma unroll
    for (int r = 0; r < 4; r++)
      for (int mask = 1; mask < 16; mask <<= 1) sum[r] += __shfl_xor(sum[r], mask);
    if (lr == 0) {
#pragma unroll
      for (int r = 0; r < 4; r++) lsum[wv * 16 + g * 4 + r] = sum[r];
    }
    __syncthreads();

    f4_t o[4] = {};
#pragma unroll
    for (int kk = 0; kk < 8; kk++) {
      bf16x8 vb = *(const bf16x8*)&Vt[wv * 16 + lr][kk * 32 + g * 8];
#pragma unroll
      for (int mi = 0; mi < 4; mi++) {
        bf16x8 pa = *(const bf16x8*)&Ps[mi * 16 + lr][kk * 32 + g * 8];
        o[mi] = mfma16(pa, vb, o[mi]);
      }
    }
#pragma unroll
    for (int mi = 0; mi < 4; mi++) {
#pragma unroll
      for (int r = 0; r < 4; r++) {
        int qrow = mi * 16 + g * 4 + r;
        float val = o[mi][r] / lsum[qrow];
        size_t off = (((size_t)(b * NWIN + wdw) * 256 + grp * 64 + qrow) * E_DIM) + hoff + wv * 16 + lr;
        winctx[off] = f2b(val);
      }
    }
    __syncthreads();
  }
}

// ---------------- overlap-average combine: winctx -> ctxb rows 1..4096 ----------------
__global__ __launch_bounds__(256) void combine_kernel(const u16* __restrict__ winctx,
                                                      u16* __restrict__ ctxb) {
  int idx = blockIdx.x * 256 + threadIdx.x;
  int e0 = (idx & 127) * 8;
  int p = (idx >> 7) & 4095;
  int b = idx >> 19;
  int whi = p >> 7;
  if (whi > 30) whi = 30;
  int off_hi = p - whi * 128;
  int wlo = whi - 1;
  bool has_lo = (wlo >= 0) && (off_hi < 128);

  uint4 vhi = *(const uint4*)(winctx + (((size_t)(b * NWIN + whi) * 256 + off_hi) * E_DIM) + e0);
  const u16* ph = (const u16*)&vhi;
  float vals[8];
#pragma unroll
  for (int j = 0; j < 8; j++) vals[j] = b2f(ph[j]);
  if (has_lo) {
    uint4 vlo = *(const uint4*)(winctx + (((size_t)(b * NWIN + wlo) * 256 + off_hi + 128) * E_DIM) + e0);
    const u16* pl = (const u16*)&vlo;
#pragma unroll
    for (int j = 0; j < 8; j++) vals[j] = (vals[j] + b2f(pl[j])) * 0.5f;
  }
  u16 out[8];
#pragma unroll
  for (int j = 0; j < 8; j++) out[j] = f2b(vals[j]);
  *(uint4*)(ctxb + ((size_t)b * L_TOT + 1 + p) * E_DIM + e0) = *(uint4*)out;
}

// ---------------- launch ----------------
extern "C" void kernel_launch(void* const* d_in, const int* in_sizes, int n_in,
                              void* d_out, int out_size, void* d_ws, size_t ws_size,
                              hipStream_t stream) {
  const float* hs = (const float*)d_in[0];
  const float* Wq = (const float*)d_in[1];
  const float* bq = (const float*)d_in[2];
  const float* Wk = (const float*)d_in[3];
  const float* bk = (const float*)d_in[4];
  const float* Wv = (const float*)d_in[5];
  const float* bv = (const float*)d_in[6];
  const float* Wo = (const float*)d_in[7];
  const float* bo = (const float*)d_in[8];

  const size_t BLE = (size_t)M_ROWS * E_DIM;
  const size_t BLE_B = BLE * 2;
  const size_t EE = (size_t)E_DIM * E_DIM;

  char* ws = (char*)d_ws;
  u16* hsb = (u16*)(ws);
  u16* wtb = (u16*)(ws + BLE_B);                       // [4][1024][1024] = QKV concat + Wo
  u16* qkv = (u16*)(ws + BLE_B + 4 * EE * 2);
  u16* Qb = qkv;
  u16* Kb = qkv + BLE;
  u16* Vb = qkv + 2 * BLE;
  u16* ctxb = (u16*)(ws + BLE_B + 4 * EE * 2 + 3 * BLE_B);
  u16* winctx = (u16*)(ws + BLE_B + 4 * EE * 2 + 4 * BLE_B);
  float* gpart = (float*)(ws + BLE_B + 4 * EE * 2 + 4 * BLE_B +
                          (size_t)B_SZ * NWIN * 256 * E_DIM * 2);

  cvt_kernel<<<8194, 256, 0, stream>>>(hs, hsb, (int)(BLE / 4));
  wtrans_kernel<<<dim3(32, 32, 4), dim3(32, 8), 0, stream>>>(Wq, Wk, Wv, Wo, wtb);
  // QKV fused: N = 3072, 65 m-tiles x 24 n-tiles = 1560 blocks (div by 8)
  gemm2_kernel<0><<<65 * 24, 256, 0, stream>>>(hsb, wtb, bq, bk, bv, qkv, M_ROWS, 24);
  gattn1_kernel<<<dim3(GCHUNKS, HHEADS, B_SZ), 256, 0, stream>>>(Qb, Kb, Vb, gpart);
  gattn2_kernel<<<32, 64, 0, stream>>>(gpart, ctxb);
  wattn_kernel<<<dim3(NWIN, HHEADS, B_SZ), 256, 0, stream>>>(Qb, Kb, Vb, winctx);
  combine_kernel<<<4096, 256, 0, stream>>>(winctx, ctxb);
  // output projection: N = 1024, 65 x 8 = 520 blocks (div by 8)
  gemm2_kernel<1><<<65 * 8, 256, 0, stream>>>(ctxb, wtb + 3 * EE, bo, bo, bo, d_out, M_ROWS, 8);
}